// Round 1
// baseline (5500.511 us; speedup 1.0000x reference)
//
#include <hip/hip_runtime.h>
#include <cstdint>
#include <cstddef>

#define NB 64      // batch
#define LN 48      // buffer length
#define DN 256     // hidden dim
#define TKN 128    // tracker dim
#define TN 95      // steps = 2L-1
#define GA 512     // 4*TK
#define GR 1280    // 5*D

__device__ __forceinline__ float sigf(float x) { return 1.0f / (1.0f + expf(-x)); }

// ---------------- schedule builder: 1 wg, 64 threads (one per batch) --------
// tag codes: -1 = zeros, 0..47 = BUF idx, 1000+k = RED k
__global__ void k_sched(const int* __restrict__ trans,
                        int* __restrict__ tbcode, int* __restrict__ s1code,
                        int* __restrict__ s2code, int* __restrict__ wkA,
                        int* __restrict__ fcode) {
    __shared__ int tg[NB][LN];
    int b = threadIdx.x;
    if (b >= NB) return;
    for (int i = 0; i < LN; ++i) tg[b][i] = -1;
    int sp = 0, bp = 0, k = 0;
    for (int t = 0; t < TN; ++t) {
        int tr = trans[b * TN + t];
        int shift = (tr == 0);
        int tb = (bp < LN) ? bp : -1;
        tbcode[t * NB + b] = tb;
        int i1 = sp - 1; if (i1 < 0) i1 = 0; if (i1 > LN - 1) i1 = LN - 1;
        int i2 = sp - 2; if (i2 < 0) i2 = 0; if (i2 > LN - 1) i2 = LN - 1;
        s1code[t * NB + b] = (sp >= 1) ? tg[b][i1] : -1;
        s2code[t * NB + b] = (sp >= 2) ? tg[b][i2] : -1;
        if (shift) {
            wkA[t * NB + b] = -1;
            if (sp >= 0 && sp < LN) tg[b][sp] = tb;
            sp = sp + 1;
            bp = bp + 1;
        } else {
            wkA[t * NB + b] = k;
            int pos = sp - 2; if (pos < 0) pos = 0;
            if (pos < LN) tg[b][pos] = 1000 + k;
            k++;
            sp = sp - 1; if (sp < 0) sp = 0;
        }
    }
    int fi = sp - 1; if (fi < 0) fi = 0; if (fi > LN - 1) fi = LN - 1;
    fcode[b] = tg[b][fi];
}

// ---------------- phase A: gates GEMM + tracker LSTM ------------------------
// grid 256 = 8 batch-groups x 32 col-groups; block 256 = 16 cols x 8 b x 2 khalf
__global__ __launch_bounds__(256) void k_gates(
    int t, int addbl,
    const float* __restrict__ bufh,
    const float* __restrict__ Wb, const float* __restrict__ W1,
    const float* __restrict__ W2, const float* __restrict__ Wl,
    const float* __restrict__ bl,
    const int* __restrict__ tbcode, const int* __restrict__ s1code,
    const int* __restrict__ s2code,
    const float* __restrict__ redh,
    float* __restrict__ th, float* __restrict__ tc) {
    int bg = blockIdx.x >> 5, cg = blockIdx.x & 31;
    int tid = threadIdx.x;
    int coll = tid & 15;          // 0..15 : q*4 + jo
    int bloc = (tid >> 4) & 7;    // 0..7
    int kh = tid >> 7;            // 0/1
    int b = bg * 8 + bloc;
    int q = coll >> 2, jo = coll & 3;
    int j = cg * 4 + jo;
    int col = q * 128 + j;
    int par = t & 1;

    float acc = 0.f;
    if (kh == 0) {
        int c = tbcode[t * NB + b];
        if (c >= 0) {
            const float* x = bufh + ((size_t)b * LN + c) * DN;
            #pragma unroll 4
            for (int k = 0; k < DN; ++k) acc += x[k] * Wb[(size_t)k * GA + col];
        }
        const float* xt = th + ((size_t)par * NB + b) * TKN;
        #pragma unroll 4
        for (int k = 0; k < TKN; ++k) acc += xt[k] * Wl[(size_t)k * GA + col];
        if (addbl) acc += bl[col];
    } else {
        int c1 = s1code[t * NB + b];
        if (c1 != -1) {
            const float* x = (c1 >= 1000) ? redh + ((size_t)(c1 - 1000) * NB + b) * DN
                                          : bufh + ((size_t)b * LN + c1) * DN;
            #pragma unroll 4
            for (int k = 0; k < DN; ++k) acc += x[k] * W1[(size_t)k * GA + col];
        }
        int c2 = s2code[t * NB + b];
        if (c2 != -1) {
            const float* x = (c2 >= 1000) ? redh + ((size_t)(c2 - 1000) * NB + b) * DN
                                          : bufh + ((size_t)b * LN + c2) * DN;
            #pragma unroll 4
            for (int k = 0; k < DN; ++k) acc += x[k] * W2[(size_t)k * GA + col];
        }
    }
    __shared__ float part[256];
    part[tid] = acc;
    __syncthreads();
    if (tid < 128) part[tid] = part[tid] + part[tid + 128];
    __syncthreads();
    // tracker LSTM for this wg's 4 j's x 8 batches
    if (tid < 128 && (tid & 15) < 4) {
        int base = tid & ~15;             // bloc*16
        int joo = tid & 3;
        float a = part[base + 0 * 4 + joo];
        float i = part[base + 1 * 4 + joo];
        float f = part[base + 2 * 4 + joo];
        float o = part[base + 3 * 4 + joo];
        int gb = bg * 8 + ((tid >> 4) & 7);
        int jj = cg * 4 + joo;
        float tco = tc[((size_t)par * NB + gb) * TKN + jj];
        float c2v = tanhf(a) * sigf(i) + sigf(f) * tco;
        float h2 = sigf(o) * tanhf(c2v);
        tc[((size_t)(par ^ 1) * NB + gb) * TKN + jj] = c2v;
        th[((size_t)(par ^ 1) * NB + gb) * TKN + jj] = h2;
    }
}

// ---------------- phase B: rgates GEMM + TreeLSTM (reduce steps only) -------
// grid 256 = 8 bg x 32 cg; cg owns j-slice of 8 -> 40 cols (5 gate groups)
__global__ __launch_bounds__(256) void k_reduce(
    int t,
    const float* __restrict__ bufh, const float* __restrict__ bufc,
    const float* __restrict__ WLm, const float* __restrict__ bLv,
    const float* __restrict__ WR, const float* __restrict__ WT,
    const int* __restrict__ s1code, const int* __restrict__ s2code,
    const int* __restrict__ wkA,
    const float* __restrict__ th,
    float* __restrict__ redh, float* __restrict__ redc) {
    int bg = blockIdx.x >> 5, cg = blockIdx.x & 31;
    int tid = threadIdx.x;
    int par2 = (t + 1) & 1;
    __shared__ float rg[320];
    __shared__ int wks[8], s1s[8], s2s[8];
    if (tid < 8) {
        int b = bg * 8 + tid;
        wks[tid] = wkA[t * NB + b];
        s1s[tid] = s1code[t * NB + b];
        s2s[tid] = s2code[t * NB + b];
    }
    __syncthreads();
    for (int d = tid; d < 320; d += 256) {
        int bloc = d / 40;
        int colL = d % 40;
        int g = colL >> 3, jo = colL & 7;
        int b = bg * 8 + bloc;
        float acc = 0.f;
        if (wks[bloc] >= 0) {
            int col = g * 256 + cg * 8 + jo;
            int c2 = s2s[bloc];   // s2h @ WL
            if (c2 != -1) {
                const float* x = (c2 >= 1000) ? redh + ((size_t)(c2 - 1000) * NB + b) * DN
                                              : bufh + ((size_t)b * LN + c2) * DN;
                #pragma unroll 4
                for (int k = 0; k < DN; ++k) acc += x[k] * WLm[(size_t)k * GR + col];
            }
            int c1 = s1s[bloc];   // s1h @ WR
            if (c1 != -1) {
                const float* x = (c1 >= 1000) ? redh + ((size_t)(c1 - 1000) * NB + b) * DN
                                              : bufh + ((size_t)b * LN + c1) * DN;
                #pragma unroll 4
                for (int k = 0; k < DN; ++k) acc += x[k] * WR[(size_t)k * GR + col];
            }
            const float* xt = th + ((size_t)par2 * NB + b) * TKN;  // th2 @ WT
            #pragma unroll 4
            for (int k = 0; k < TKN; ++k) acc += xt[k] * WT[(size_t)k * GR + col];
            acc += bLv[col];
        }
        rg[d] = acc;
    }
    __syncthreads();
    if (tid < 64) {
        int bloc = tid >> 3, jo = tid & 7;
        if (wks[bloc] >= 0) {
            int b = bg * 8 + bloc;
            int j = cg * 8 + jo;
            float a  = rg[bloc * 40 + 0 * 8 + jo];
            float i  = rg[bloc * 40 + 1 * 8 + jo];
            float f1 = rg[bloc * 40 + 2 * 8 + jo];
            float f2 = rg[bloc * 40 + 3 * 8 + jo];
            float o  = rg[bloc * 40 + 4 * 8 + jo];
            int c2c = s2s[bloc], c1c = s1s[bloc];
            float s2cv = (c2c == -1) ? 0.f
                        : ((c2c >= 1000) ? redc[((size_t)(c2c - 1000) * NB + b) * DN + j]
                                         : bufc[((size_t)b * LN + c2c) * DN + j]);
            float s1cv = (c1c == -1) ? 0.f
                        : ((c1c >= 1000) ? redc[((size_t)(c1c - 1000) * NB + b) * DN + j]
                                         : bufc[((size_t)b * LN + c1c) * DN + j]);
            float cc = tanhf(a) * sigf(i) + sigf(f1) * s2cv + sigf(f2) * s1cv;
            float hh = sigf(o) * tanhf(cc);
            int wk = wks[bloc];
            redh[((size_t)wk * NB + b) * DN + j] = hh;
            redc[((size_t)wk * NB + b) * DN + j] = cc;
        }
    }
}

// ---------------- final gather ---------------------------------------------
__global__ void k_final(const float* __restrict__ bufh, const float* __restrict__ bufc,
                        const float* __restrict__ redh, const float* __restrict__ redc,
                        const int* __restrict__ fcode, float* __restrict__ out) {
    int idx = blockIdx.x * 256 + threadIdx.x;
    if (idx >= NB * 2 * DN) return;
    int b = idx / (2 * DN);
    int e = idx % (2 * DN);
    int c = fcode[b];
    float v = 0.f;
    if (c != -1) {
        if (e < DN)
            v = (c >= 1000) ? redh[((size_t)(c - 1000) * NB + b) * DN + e]
                            : bufh[((size_t)b * LN + c) * DN + e];
        else {
            int e2 = e - DN;
            v = (c >= 1000) ? redc[((size_t)(c - 1000) * NB + b) * DN + e2]
                            : bufc[((size_t)b * LN + c) * DN + e2];
        }
    }
    out[idx] = v;
}

extern "C" void kernel_launch(void* const* d_in, const int* in_sizes, int n_in,
                              void* d_out, int out_size, void* d_ws, size_t ws_size,
                              hipStream_t stream) {
    const float* bufh = (const float*)d_in[0];
    const float* bufc = (const float*)d_in[1];
    const float* Wb   = (const float*)d_in[2];
    const float* W1   = (const float*)d_in[3];
    const float* W2   = (const float*)d_in[4];
    const float* Wl   = (const float*)d_in[5];
    const float* bl   = (const float*)d_in[6];
    const float* WLm  = (const float*)d_in[7];
    const float* bLv  = (const float*)d_in[8];
    const float* WR   = (const float*)d_in[9];
    const float* WT   = (const float*)d_in[10];
    const int* trans  = (const int*)d_in[11];
    float* out = (float*)d_out;

    char* p = (char*)d_ws;
    auto carve = [&](size_t bytes) -> char* {
        char* r = p;
        p += (bytes + 255) & ~(size_t)255;
        return r;
    };
    int* tbcode = (int*)carve((size_t)TN * NB * 4);
    int* s1code = (int*)carve((size_t)TN * NB * 4);
    int* s2code = (int*)carve((size_t)TN * NB * 4);
    int* wkA    = (int*)carve((size_t)TN * NB * 4);
    int* fcode  = (int*)carve((size_t)NB * 4);
    float* th   = (float*)carve((size_t)2 * NB * TKN * 4);
    float* tc   = (float*)carve((size_t)2 * NB * TKN * 4);
    float* redh = (float*)carve((size_t)TN * NB * DN * 4);
    float* redc = (float*)carve((size_t)TN * NB * DN * 4);

    hipMemsetAsync(th, 0, (size_t)2 * NB * TKN * 4, stream);
    hipMemsetAsync(tc, 0, (size_t)2 * NB * TKN * 4, stream);

    k_sched<<<1, 64, 0, stream>>>(trans, tbcode, s1code, s2code, wkA, fcode);

    for (int t = 0; t < TN; ++t) {
        k_gates<<<256, 256, 0, stream>>>(t, (t > 0) ? 1 : 0, bufh,
                                         Wb, W1, W2, Wl, bl,
                                         tbcode, s1code, s2code, redh, th, tc);
        k_reduce<<<256, 256, 0, stream>>>(t, bufh, bufc, WLm, bLv, WR, WT,
                                          s1code, s2code, wkA, th, redh, redc);
    }
    k_final<<<(NB * 2 * DN + 255) / 256, 256, 0, stream>>>(bufh, bufc, redh, redc, fcode, out);
}

// Round 2
// 2068.600 us; speedup vs baseline: 2.6590x; 2.6590x over previous
//
#include <hip/hip_runtime.h>
#include <cstdint>
#include <cstddef>

#define NB 64      // batch
#define LN 48      // buffer length
#define DN 256     // hidden dim
#define TKN 128    // tracker dim
#define TN 95      // steps = 2L-1
#define GA 512     // 4*TK
#define GR 1280    // 5*D

__device__ __forceinline__ float sigf(float x) { return 1.0f / (1.0f + expf(-x)); }

__device__ __forceinline__ const float* row_ptr(int code, int b,
    const float* __restrict__ bufh, const float* __restrict__ redh) {
    if (code < 0) return nullptr;
    if (code >= 1000) return redh + ((size_t)(code - 1000) * NB + b) * DN;
    return bufh + ((size_t)b * LN + code) * DN;
}

// ---------------- schedule builder: 1 wg, 64 threads (one per batch) --------
// tag codes: -1 = zeros, 0..47 = BUF idx, 1000+k = RED k
__global__ void k_sched(const int* __restrict__ trans,
                        int* __restrict__ tbcode, int* __restrict__ s1code,
                        int* __restrict__ s2code, int* __restrict__ wkA,
                        int* __restrict__ fcode) {
    __shared__ int tg[NB][LN];
    int b = threadIdx.x;
    if (b >= NB) return;
    for (int i = 0; i < LN; ++i) tg[b][i] = -1;
    int sp = 0, bp = 0, k = 0;
    for (int t = 0; t < TN; ++t) {
        int tr = trans[b * TN + t];
        int shift = (tr == 0);
        int tb = (bp < LN) ? bp : -1;
        tbcode[t * NB + b] = tb;
        int i1 = sp - 1; if (i1 < 0) i1 = 0; if (i1 > LN - 1) i1 = LN - 1;
        int i2 = sp - 2; if (i2 < 0) i2 = 0; if (i2 > LN - 1) i2 = LN - 1;
        s1code[t * NB + b] = (sp >= 1) ? tg[b][i1] : -1;
        s2code[t * NB + b] = (sp >= 2) ? tg[b][i2] : -1;
        if (shift) {
            wkA[t * NB + b] = -1;
            if (sp >= 0 && sp < LN) tg[b][sp] = tb;
            sp = sp + 1;
            bp = bp + 1;
        } else {
            wkA[t * NB + b] = k;
            int pos = sp - 2; if (pos < 0) pos = 0;
            if (pos < LN) tg[b][pos] = 1000 + k;
            k++;
            sp = sp - 1; if (sp < 0) sp = 0;
        }
    }
    int fi = sp - 1; if (fi < 0) fi = 0; if (fi > LN - 1) fi = LN - 1;
    fcode[b] = tg[b][fi];
}

// ---------------- phase A: gates GEMM + tracker LSTM ------------------------
// grid 256 = 32 batch-groups(2 b) x 8 jg(16 tracker-j); block 256 = 4 waves
// lane -> col = q*128 + jg*16 + jj ; waves split K=896 into 224-chunks
__global__ __launch_bounds__(256) void k_gates2(
    int t, int addbl,
    const float* __restrict__ bufh,
    const float* __restrict__ Wb, const float* __restrict__ W1,
    const float* __restrict__ W2, const float* __restrict__ Wl,
    const float* __restrict__ bl,
    const int* __restrict__ tbcode, const int* __restrict__ s1code,
    const int* __restrict__ s2code,
    const float* __restrict__ redh,
    float* __restrict__ th, float* __restrict__ tc) {
    int bg = blockIdx.x >> 3;     // 0..31
    int jg = blockIdx.x & 7;      // 0..7
    int tid = threadIdx.x;
    int lane = tid & 63, w = tid >> 6;
    int par = t & 1;

    __shared__ float xs[896][2];
    __shared__ float part[4][64][2];
    __shared__ float gsum[2][64];

    // stage x = [tb_h(256) | s1h(256) | s2h(256) | th(128)] for 2 batches
    for (int bl_ = 0; bl_ < 2; ++bl_) {
        int b = bg * 2 + bl_;
        const float* tbp = row_ptr(tbcode[t * NB + b], b, bufh, redh);
        const float* s1p = row_ptr(s1code[t * NB + b], b, bufh, redh);
        const float* s2p = row_ptr(s2code[t * NB + b], b, bufh, redh);
        const float* thp = th + ((size_t)par * NB + b) * TKN;
        for (int k = tid; k < 896; k += 256) {
            float v;
            if (k < 256)      v = tbp ? tbp[k] : 0.f;
            else if (k < 512) v = s1p ? s1p[k - 256] : 0.f;
            else if (k < 768) v = s2p ? s2p[k - 512] : 0.f;
            else              v = thp[k - 768];
            xs[k][bl_] = v;
        }
    }
    __syncthreads();

    int q = lane >> 4, jj = lane & 15;
    int col = q * 128 + jg * 16 + jj;
    float a0 = 0.f, a1 = 0.f;
    int k0 = w * 224, k1 = k0 + 224;
    const float* const segbase[4] = {Wb, W1, W2, Wl};
    const int segs[5] = {0, 256, 512, 768, 896};
    #pragma unroll
    for (int s = 0; s < 4; ++s) {
        int lo = k0 > segs[s] ? k0 : segs[s];
        int hi = k1 < segs[s + 1] ? k1 : segs[s + 1];
        const float* base = segbase[s] + col;
        #pragma unroll 4
        for (int k = lo; k < hi; ++k) {
            float wv = base[(size_t)(k - segs[s]) * GA];
            float2 xv = *(const float2*)&xs[k][0];
            a0 += xv.x * wv;
            a1 += xv.y * wv;
        }
    }
    part[w][lane][0] = a0;
    part[w][lane][1] = a1;
    __syncthreads();

    if (w == 0) {
        float s0 = part[0][lane][0] + part[1][lane][0] + part[2][lane][0] + part[3][lane][0];
        float s1 = part[0][lane][1] + part[1][lane][1] + part[2][lane][1] + part[3][lane][1];
        if (addbl) { float bv = bl[col]; s0 += bv; s1 += bv; }
        gsum[0][lane] = s0;
        gsum[1][lane] = s1;
    }
    __syncthreads();

    if (tid < 32) {
        int bl_ = tid >> 4, j2 = tid & 15;
        int b = bg * 2 + bl_;
        int j = jg * 16 + j2;
        float a = gsum[bl_][j2];
        float i = gsum[bl_][16 + j2];
        float f = gsum[bl_][32 + j2];
        float o = gsum[bl_][48 + j2];
        float tco = tc[((size_t)par * NB + b) * TKN + j];
        float c2 = tanhf(a) * sigf(i) + sigf(f) * tco;
        float h2 = sigf(o) * tanhf(c2);
        tc[((size_t)(par ^ 1) * NB + b) * TKN + j] = c2;
        th[((size_t)(par ^ 1) * NB + b) * TKN + j] = h2;
    }
}

// ---------------- phase B: rgates GEMM + TreeLSTM (reduce steps only) -------
// grid 64 = 16 bg(4 b) x 4 jg(64 j); block 512 = 8 waves splitting K=640
// lane = j ; each lane accumulates all 5 gates x 4 batches
__global__ __launch_bounds__(512) void k_reduce2(
    int t,
    const float* __restrict__ bufh, const float* __restrict__ bufc,
    const float* __restrict__ WLm, const float* __restrict__ bLv,
    const float* __restrict__ WRm, const float* __restrict__ WTm,
    const int* __restrict__ s1code, const int* __restrict__ s2code,
    const int* __restrict__ wkA,
    const float* __restrict__ th,
    float* __restrict__ redh, float* __restrict__ redc) {
    int bg = blockIdx.x >> 2;    // 0..15
    int jg = blockIdx.x & 3;     // 0..3
    int tid = threadIdx.x;
    int lane = tid & 63, w = tid >> 6;   // 8 waves
    int par2 = (t + 1) & 1;

    __shared__ float xs[640][4];
    __shared__ float part[8][64][21];    // padded 20 -> 21 (conflict-free)
    __shared__ int s1s[4], s2s[4], wks[4];

    if (tid < 4) {
        int b = bg * 4 + tid;
        s1s[tid] = s1code[t * NB + b];
        s2s[tid] = s2code[t * NB + b];
        wks[tid] = wkA[t * NB + b];
    }
    __syncthreads();
    if (wks[0] < 0 && wks[1] < 0 && wks[2] < 0 && wks[3] < 0) return;

    // stage x = [s2h(256) | s1h(256) | th2(128)] for 4 batches
    for (int bl_ = 0; bl_ < 4; ++bl_) {
        int b = bg * 4 + bl_;
        const float* s2p = row_ptr(s2s[bl_], b, bufh, redh);
        const float* s1p = row_ptr(s1s[bl_], b, bufh, redh);
        const float* thp = th + ((size_t)par2 * NB + b) * TKN;
        for (int k = tid; k < 640; k += 512) {
            float v;
            if (k < 256)      v = s2p ? s2p[k] : 0.f;
            else if (k < 512) v = s1p ? s1p[k - 256] : 0.f;
            else              v = thp[k - 512];
            xs[k][bl_] = v;
        }
    }
    __syncthreads();

    int j = jg * 64 + lane;
    float acc[4][5];
    #pragma unroll
    for (int b = 0; b < 4; ++b)
        #pragma unroll
        for (int g = 0; g < 5; ++g) acc[b][g] = 0.f;

    int k0 = w * 80, k1 = k0 + 80;
    const float* const segbase[3] = {WLm, WRm, WTm};
    const int segs[4] = {0, 256, 512, 640};
    #pragma unroll
    for (int s = 0; s < 3; ++s) {
        int lo = k0 > segs[s] ? k0 : segs[s];
        int hi = k1 < segs[s + 1] ? k1 : segs[s + 1];
        const float* base = segbase[s] + j;
        #pragma unroll 2
        for (int k = lo; k < hi; ++k) {
            const float* wr = base + (size_t)(k - segs[s]) * GR;
            float w0 = wr[0], w1 = wr[256], w2 = wr[512], w3 = wr[768], w4 = wr[1024];
            float4 xv = *(const float4*)&xs[k][0];
            acc[0][0] += xv.x * w0; acc[0][1] += xv.x * w1; acc[0][2] += xv.x * w2; acc[0][3] += xv.x * w3; acc[0][4] += xv.x * w4;
            acc[1][0] += xv.y * w0; acc[1][1] += xv.y * w1; acc[1][2] += xv.y * w2; acc[1][3] += xv.y * w3; acc[1][4] += xv.y * w4;
            acc[2][0] += xv.z * w0; acc[2][1] += xv.z * w1; acc[2][2] += xv.z * w2; acc[2][3] += xv.z * w3; acc[2][4] += xv.z * w4;
            acc[3][0] += xv.w * w0; acc[3][1] += xv.w * w1; acc[3][2] += xv.w * w2; acc[3][3] += xv.w * w3; acc[3][4] += xv.w * w4;
        }
    }
    #pragma unroll
    for (int b = 0; b < 4; ++b)
        #pragma unroll
        for (int g = 0; g < 5; ++g) part[w][lane][b * 5 + g] = acc[b][g];
    __syncthreads();

    if (tid < 256) {
        int bl_ = tid >> 6, lj = tid & 63;
        if (wks[bl_] >= 0) {
            int b = bg * 4 + bl_;
            int jj = jg * 64 + lj;
            float g[5];
            #pragma unroll
            for (int gi = 0; gi < 5; ++gi) {
                float s = 0.f;
                #pragma unroll
                for (int ww = 0; ww < 8; ++ww) s += part[ww][lj][bl_ * 5 + gi];
                g[gi] = s + bLv[gi * 256 + jj];
            }
            int c2c = s2s[bl_], c1c = s1s[bl_];
            float s2cv = (c2c == -1) ? 0.f
                        : ((c2c >= 1000) ? redc[((size_t)(c2c - 1000) * NB + b) * DN + jj]
                                         : bufc[((size_t)b * LN + c2c) * DN + jj]);
            float s1cv = (c1c == -1) ? 0.f
                        : ((c1c >= 1000) ? redc[((size_t)(c1c - 1000) * NB + b) * DN + jj]
                                         : bufc[((size_t)b * LN + c1c) * DN + jj]);
            float cc = tanhf(g[0]) * sigf(g[1]) + sigf(g[2]) * s2cv + sigf(g[3]) * s1cv;
            float hh = sigf(g[4]) * tanhf(cc);
            int wk = wks[bl_];
            redh[((size_t)wk * NB + b) * DN + jj] = hh;
            redc[((size_t)wk * NB + b) * DN + jj] = cc;
        }
    }
}

// ---------------- final gather ---------------------------------------------
__global__ void k_final(const float* __restrict__ bufh, const float* __restrict__ bufc,
                        const float* __restrict__ redh, const float* __restrict__ redc,
                        const int* __restrict__ fcode, float* __restrict__ out) {
    int idx = blockIdx.x * 256 + threadIdx.x;
    if (idx >= NB * 2 * DN) return;
    int b = idx / (2 * DN);
    int e = idx % (2 * DN);
    int c = fcode[b];
    float v = 0.f;
    if (c != -1) {
        if (e < DN)
            v = (c >= 1000) ? redh[((size_t)(c - 1000) * NB + b) * DN + e]
                            : bufh[((size_t)b * LN + c) * DN + e];
        else {
            int e2 = e - DN;
            v = (c >= 1000) ? redc[((size_t)(c - 1000) * NB + b) * DN + e2]
                            : bufc[((size_t)b * LN + c) * DN + e2];
        }
    }
    out[idx] = v;
}

extern "C" void kernel_launch(void* const* d_in, const int* in_sizes, int n_in,
                              void* d_out, int out_size, void* d_ws, size_t ws_size,
                              hipStream_t stream) {
    const float* bufh = (const float*)d_in[0];
    const float* bufc = (const float*)d_in[1];
    const float* Wb   = (const float*)d_in[2];
    const float* W1   = (const float*)d_in[3];
    const float* W2   = (const float*)d_in[4];
    const float* Wl   = (const float*)d_in[5];
    const float* bl   = (const float*)d_in[6];
    const float* WLm  = (const float*)d_in[7];
    const float* bLv  = (const float*)d_in[8];
    const float* WR   = (const float*)d_in[9];
    const float* WT   = (const float*)d_in[10];
    const int* trans  = (const int*)d_in[11];
    float* out = (float*)d_out;

    char* p = (char*)d_ws;
    auto carve = [&](size_t bytes) -> char* {
        char* r = p;
        p += (bytes + 255) & ~(size_t)255;
        return r;
    };
    int* tbcode = (int*)carve((size_t)TN * NB * 4);
    int* s1code = (int*)carve((size_t)TN * NB * 4);
    int* s2code = (int*)carve((size_t)TN * NB * 4);
    int* wkA    = (int*)carve((size_t)TN * NB * 4);
    int* fcode  = (int*)carve((size_t)NB * 4);
    float* th   = (float*)carve((size_t)2 * NB * TKN * 4);
    float* tc   = (float*)carve((size_t)2 * NB * TKN * 4);
    float* redh = (float*)carve((size_t)TN * NB * DN * 4);
    float* redc = (float*)carve((size_t)TN * NB * DN * 4);

    hipMemsetAsync(th, 0, (size_t)2 * NB * TKN * 4, stream);
    hipMemsetAsync(tc, 0, (size_t)2 * NB * TKN * 4, stream);

    k_sched<<<1, 64, 0, stream>>>(trans, tbcode, s1code, s2code, wkA, fcode);

    for (int t = 0; t < TN; ++t) {
        k_gates2<<<256, 256, 0, stream>>>(t, (t > 0) ? 1 : 0, bufh,
                                          Wb, W1, W2, Wl, bl,
                                          tbcode, s1code, s2code, redh, th, tc);
        k_reduce2<<<64, 512, 0, stream>>>(t, bufh, bufc, WLm, bLv, WR, WT,
                                          s1code, s2code, wkA, th, redh, redc);
    }
    k_final<<<(NB * 2 * DN + 255) / 256, 256, 0, stream>>>(bufh, bufc, redh, redc, fcode, out);
}